// Round 10
// baseline (50.658 us; speedup 1.0000x reference)
//
#include <hip/hip_runtime.h>

#define B_    4
#define N_    1024
#define L_    8
#define FV_   64
#define OUT_  8
#define INFEAT_ (L_ + 2*FV_)   // 136
#define ITILE_ 2               // i-rows per block; grid = B*N/ITILE_ = 2048

typedef float f32x4 __attribute__((ext_vector_type(4)));

// Kernel 1: 256 blocks x 128 threads, o-major mapping (unchanged).
__global__ __launch_bounds__(128) void precompute_tv_kernel(
    const float* __restrict__ V, const float* __restrict__ W,
    float* __restrict__ tv1, float* __restrict__ tv2)
{
    int gt   = blockIdx.x * 128 + threadIdx.x;   // 0 .. 32767
    int o    = gt >> 12;                         // block-uniform
    int pair = gt & 4095;                        // b*N + j
    int b    = pair >> 10;
    int j    = pair & 1023;

    __shared__ float wv1[FV_], wv2[FV_];         // 512 B
    int t = threadIdx.x;
    if (t < FV_)                wv1[t]       = W[o * INFEAT_ + L_ + t];
    else                        wv2[t - FV_] = W[o * INFEAT_ + L_ + FV_ + (t - FV_)];
    __syncthreads();

    const float* vrow = V + (size_t)pair * FV_;

    float s1 = 0.f, s2 = 0.f;
    #pragma unroll
    for (int f = 0; f < FV_; f += 4) {
        f32x4 x = *reinterpret_cast<const f32x4*>(vrow + f);
        s1 += x.x * wv1[f]     + x.y * wv1[f + 1]
            + x.z * wv1[f + 2] + x.w * wv1[f + 3];
        s2 += x.x * wv2[f]     + x.y * wv2[f + 1]
            + x.z * wv2[f + 2] + x.w * wv2[f + 3];
    }
    tv1[(b * OUT_ + o) * N_ + j] = s1;
    tv2[(size_t)pair * OUT_ + o] = s2;
}

// Kernel 2 v4: block owns (b, 2 consecutive i); 2048 blocks = 8 blocks/CU.
// tv1[b][:][j..j+3] loaded once, reused 2x -> tv1 L2 stream halved.
// Plain A loads (L3-cacheable), NT stores (evict-first, protect A in L3).
__global__ __launch_bounds__(256) void graphcnn_main_kernel(
    const float* __restrict__ A, const float* __restrict__ W,
    const float* __restrict__ bias,
    const float* __restrict__ tv1, const float* __restrict__ tv2,
    float* __restrict__ out)
{
    int g  = blockIdx.x;               // 0 .. 2047
    int b  = g >> 9;                   // 0 .. 3
    int i0 = (g & 511) * ITILE_;       // 0 .. 1022
    int t  = threadIdx.x;
    int j  = t * 4;

    const float* tv1b = tv1 + b * OUT_ * N_;
    f32x4 t1[OUT_];
    #pragma unroll
    for (int o = 0; o < OUT_; ++o)
        t1[o] = *reinterpret_cast<const f32x4*>(tv1b + o * N_ + j);

    #pragma unroll 1
    for (int ii = 0; ii < ITILE_; ++ii) {
        int bi = b * N_ + i0 + ii;
        const float* arow = A + (size_t)bi * (L_ * N_);
        float* orow = out + (size_t)bi * (OUT_ * N_);

        f32x4 a[L_];
        #pragma unroll
        for (int l = 0; l < L_; ++l)
            a[l] = *reinterpret_cast<const f32x4*>(arow + l * N_ + j);

        #pragma unroll
        for (int o = 0; o < OUT_; ++o) {
            float bo = bias[o] + tv2[(size_t)bi * OUT_ + o];   // wave-uniform
            f32x4 r = t1[o];
            r.x += bo; r.y += bo; r.z += bo; r.w += bo;
            #pragma unroll
            for (int l = 0; l < L_; ++l) {
                float w = W[o * INFEAT_ + l];                  // wave-uniform
                r.x = fmaf(a[l].x, w, r.x);
                r.y = fmaf(a[l].y, w, r.y);
                r.z = fmaf(a[l].z, w, r.z);
                r.w = fmaf(a[l].w, w, r.w);
            }
            r.x = fmaxf(r.x, 0.f);
            r.y = fmaxf(r.y, 0.f);
            r.z = fmaxf(r.z, 0.f);
            r.w = fmaxf(r.w, 0.f);
            __builtin_nontemporal_store(r, reinterpret_cast<f32x4*>(orow + o * N_ + j));
        }
    }
}

extern "C" void kernel_launch(void* const* d_in, const int* in_sizes, int n_in,
                              void* d_out, int out_size, void* d_ws, size_t ws_size,
                              hipStream_t stream) {
    const float* A    = (const float*)d_in[0];
    const float* V    = (const float*)d_in[1];
    const float* W    = (const float*)d_in[2];
    const float* bias = (const float*)d_in[3];
    float* out = (float*)d_out;

    float* tv1 = (float*)d_ws;                    // B*OUT*N floats = 32768
    float* tv2 = tv1 + (size_t)B_ * OUT_ * N_;    // B*N*OUT floats = 32768

    precompute_tv_kernel<<<(B_ * N_ * OUT_) / 128, 128, 0, stream>>>(V, W, tv1, tv2);
    graphcnn_main_kernel<<<(B_ * N_) / ITILE_, 256, 0, stream>>>(A, W, bias, tv1, tv2, out);
}

// Round 11
// 48.642 us; speedup vs baseline: 1.0414x; 1.0414x over previous
//
#include <hip/hip_runtime.h>

#define B_    4
#define N_    1024
#define L_    8
#define FV_   64
#define OUT_  8
#define INFEAT_ (L_ + 2*FV_)   // 136

typedef float f32x4 __attribute__((ext_vector_type(4)));

// Kernel 1: 256 blocks x 128 threads, o-major mapping.
__global__ __launch_bounds__(128) void precompute_tv_kernel(
    const float* __restrict__ V, const float* __restrict__ W,
    float* __restrict__ tv1, float* __restrict__ tv2)
{
    int gt   = blockIdx.x * 128 + threadIdx.x;   // 0 .. 32767
    int o    = gt >> 12;                         // block-uniform
    int pair = gt & 4095;                        // b*N + j
    int b    = pair >> 10;
    int j    = pair & 1023;

    __shared__ float wv1[FV_], wv2[FV_];         // 512 B
    int t = threadIdx.x;
    if (t < FV_)                wv1[t]       = W[o * INFEAT_ + L_ + t];
    else                        wv2[t - FV_] = W[o * INFEAT_ + L_ + FV_ + (t - FV_)];
    __syncthreads();

    const float* vrow = V + (size_t)pair * FV_;

    float s1 = 0.f, s2 = 0.f;
    #pragma unroll
    for (int f = 0; f < FV_; f += 4) {
        f32x4 x = *reinterpret_cast<const f32x4*>(vrow + f);
        s1 += x.x * wv1[f]     + x.y * wv1[f + 1]
            + x.z * wv1[f + 2] + x.w * wv1[f + 3];
        s2 += x.x * wv2[f]     + x.y * wv2[f + 1]
            + x.z * wv2[f + 2] + x.w * wv2[f + 3];
    }
    tv1[(b * OUT_ + o) * N_ + j] = s1;
    tv2[(size_t)pair * OUT_ + o] = s2;
}

// Kernel 2 (R9 config — best measured 48.7 µs): one block per (b,i).
// Plain A/tv1 loads (L2-cached), NT stores (evict-first write path),
// weights/bias/tv2 via wave-uniform scalar loads. No LDS, no barrier.
// out[b,i,o,j] = relu( sum_l A[b,i,l,j]*W[o,l] + tv1[b,o,j] + tv2[b,i,o] + bias[o] )
__global__ __launch_bounds__(256) void graphcnn_main_kernel(
    const float* __restrict__ A, const float* __restrict__ W,
    const float* __restrict__ bias,
    const float* __restrict__ tv1, const float* __restrict__ tv2,
    float* __restrict__ out)
{
    int bi = blockIdx.x;          // b*N + i
    int b  = bi >> 10;
    int t  = threadIdx.x;
    int j  = t * 4;               // 256 threads * 4 = 1024 = N

    const float* arow = A + (size_t)bi * (L_ * N_);
    const float* tv1b = tv1 + b * OUT_ * N_;
    float* orow = out + (size_t)bi * (OUT_ * N_);

    // 8 streaming A loads (plain/cached), hoisted: needed by every o.
    f32x4 a[L_];
    #pragma unroll
    for (int l = 0; l < L_; ++l)
        a[l] = *reinterpret_cast<const f32x4*>(arow + l * N_ + j);

    #pragma unroll
    for (int o = 0; o < OUT_; ++o) {
        float bo = bias[o] + tv2[(size_t)bi * OUT_ + o];   // wave-uniform -> SGPR
        f32x4 r = *reinterpret_cast<const f32x4*>(tv1b + o * N_ + j);
        r.x += bo; r.y += bo; r.z += bo; r.w += bo;
        #pragma unroll
        for (int l = 0; l < L_; ++l) {
            float w = W[o * INFEAT_ + l];   // wave-uniform -> SGPR
            r.x = fmaf(a[l].x, w, r.x);
            r.y = fmaf(a[l].y, w, r.y);
            r.z = fmaf(a[l].z, w, r.z);
            r.w = fmaf(a[l].w, w, r.w);
        }
        r.x = fmaxf(r.x, 0.f);
        r.y = fmaxf(r.y, 0.f);
        r.z = fmaxf(r.z, 0.f);
        r.w = fmaxf(r.w, 0.f);
        __builtin_nontemporal_store(r, reinterpret_cast<f32x4*>(orow + o * N_ + j));
    }
}

extern "C" void kernel_launch(void* const* d_in, const int* in_sizes, int n_in,
                              void* d_out, int out_size, void* d_ws, size_t ws_size,
                              hipStream_t stream) {
    const float* A    = (const float*)d_in[0];
    const float* V    = (const float*)d_in[1];
    const float* W    = (const float*)d_in[2];
    const float* bias = (const float*)d_in[3];
    float* out = (float*)d_out;

    float* tv1 = (float*)d_ws;                    // B*OUT*N floats = 32768
    float* tv2 = tv1 + (size_t)B_ * OUT_ * N_;    // B*N*OUT floats = 32768

    precompute_tv_kernel<<<(B_ * N_ * OUT_) / 128, 128, 0, stream>>>(V, W, tv1, tv2);
    graphcnn_main_kernel<<<B_ * N_, 256, 0, stream>>>(A, W, bias, tv1, tv2, out);
}